// Round 2
// baseline (71.012 us; speedup 1.0000x reference)
//
#include <hip/hip_runtime.h>

#define EPS 1e-5f
#define THREADS 256
#define PAIRS 4                      // float4-pairs per thread, batched loads
#define CHUNK (THREADS * PAIRS)      // float4 elements per block chunk = 1024

// ---------------------------------------------------------------------------
// Kernel 1: full unmasked sum of nll = log(tau) + (dt+eps)/tau over all N.
// Each block owns contiguous chunks of 1024 float4 (16 KB/array). Each thread
// issues 8 independent dwordx4 loads (128 B in flight) before any compute —
// maximizes memory-level parallelism. 4 accumulators break the VALU chain.
// ---------------------------------------------------------------------------
__global__ __launch_bounds__(THREADS) void tau_loss_main(
    const float4* __restrict__ t4,
    const float4* __restrict__ d4,
    const float* __restrict__ tau,
    const float* __restrict__ dt,
    float* __restrict__ out,
    int n, float inv_div) {
    const int n4 = n >> 2;
    const int full = n4 / CHUNK;      // number of complete 1024-float4 chunks

    float a0 = 0.f, a1 = 0.f, a2 = 0.f, a3 = 0.f;

    for (int c = blockIdx.x; c < full; c += gridDim.x) {
        const int base = c * CHUNK + (int)threadIdx.x;
        // ---- issue all 8 loads, no intervening use ----
        float4 t0 = t4[base + 0 * THREADS];
        float4 t1 = t4[base + 1 * THREADS];
        float4 t2 = t4[base + 2 * THREADS];
        float4 t3 = t4[base + 3 * THREADS];
        float4 e0 = d4[base + 0 * THREADS];
        float4 e1 = d4[base + 1 * THREADS];
        float4 e2 = d4[base + 2 * THREADS];
        float4 e3 = d4[base + 3 * THREADS];
        // ---- compute ----
        a0 += __logf(t0.x) + __fdividef(e0.x + EPS, t0.x);
        a1 += __logf(t0.y) + __fdividef(e0.y + EPS, t0.y);
        a2 += __logf(t0.z) + __fdividef(e0.z + EPS, t0.z);
        a3 += __logf(t0.w) + __fdividef(e0.w + EPS, t0.w);
        a0 += __logf(t1.x) + __fdividef(e1.x + EPS, t1.x);
        a1 += __logf(t1.y) + __fdividef(e1.y + EPS, t1.y);
        a2 += __logf(t1.z) + __fdividef(e1.z + EPS, t1.z);
        a3 += __logf(t1.w) + __fdividef(e1.w + EPS, t1.w);
        a0 += __logf(t2.x) + __fdividef(e2.x + EPS, t2.x);
        a1 += __logf(t2.y) + __fdividef(e2.y + EPS, t2.y);
        a2 += __logf(t2.z) + __fdividef(e2.z + EPS, t2.z);
        a3 += __logf(t2.w) + __fdividef(e2.w + EPS, t2.w);
        a0 += __logf(t3.x) + __fdividef(e3.x + EPS, t3.x);
        a1 += __logf(t3.y) + __fdividef(e3.y + EPS, t3.y);
        a2 += __logf(t3.z) + __fdividef(e3.z + EPS, t3.z);
        a3 += __logf(t3.w) + __fdividef(e3.w + EPS, t3.w);
    }

    // scalar tail: everything past full*CHUNK*4 floats (handled by block 0)
    if (blockIdx.x == 0) {
        for (int i = full * (CHUNK * 4) + (int)threadIdx.x; i < n; i += THREADS) {
            float t = tau[i];
            a0 += __logf(t) + __fdividef(dt[i] + EPS, t);
        }
    }

    float acc = (a0 + a1) + (a2 + a3);

    // wave(64) reduce
    #pragma unroll
    for (int off = 32; off > 0; off >>= 1)
        acc += __shfl_down(acc, off, 64);

    __shared__ float smem[THREADS / 64];
    int wave = threadIdx.x >> 6;
    int lane = threadIdx.x & 63;
    if (lane == 0) smem[wave] = acc;
    __syncthreads();
    if (threadIdx.x == 0) {
        float s = smem[0] + smem[1] + smem[2] + smem[3];
        atomicAdd(out, s * inv_div);
    }
}

// ---------------------------------------------------------------------------
// Kernel 2: subtract boundary (first & last of each segment) contributions.
// ---------------------------------------------------------------------------
__global__ __launch_bounds__(THREADS) void tau_loss_boundary(
    const float* __restrict__ tau,
    const float* __restrict__ dt,
    const int* __restrict__ offsets,
    float* __restrict__ out,
    int nseg, float inv_div) {
    int k = blockIdx.x * blockDim.x + threadIdx.x;

    float sub = 0.0f;
    if (k < nseg) {
        int s = offsets[k];
        int e = offsets[k + 1] - 1;
        float ts = tau[s];
        sub = __logf(ts) + __fdividef(dt[s] + EPS, ts);
        if (e != s) {
            float te = tau[e];
            sub += __logf(te) + __fdividef(dt[e] + EPS, te);
        }
    }

    #pragma unroll
    for (int off = 32; off > 0; off >>= 1)
        sub += __shfl_down(sub, off, 64);

    __shared__ float smem[THREADS / 64];
    int wave = threadIdx.x >> 6;
    int lane = threadIdx.x & 63;
    if (lane == 0) smem[wave] = sub;
    __syncthreads();
    if (threadIdx.x == 0) {
        float s = smem[0] + smem[1] + smem[2] + smem[3];
        atomicAdd(out, -s * inv_div);
    }
}

extern "C" void kernel_launch(void* const* d_in, const int* in_sizes, int n_in,
                              void* d_out, int out_size, void* d_ws, size_t ws_size,
                              hipStream_t stream) {
    const float* tau = (const float*)d_in[0];
    const float* dt  = (const float*)d_in[1];
    const int* offsets = (const int*)d_in[2];
    float* out = (float*)d_out;

    const int n = in_sizes[0];
    const int n_off = in_sizes[2];          // B + 1
    const int nseg = n_off - 1;
    const float inv_div = 1.0f / (float)n_off;

    // zero the accumulator (harness poisons d_out; does not re-zero between replays)
    hipMemsetAsync(d_out, 0, sizeof(float), stream);

    // grid sized for exact coverage of 16.7M elements: 4096 blocks x 1024 f4/chunk
    int n4 = n >> 2;
    int full = n4 / CHUNK;
    int gblocks = full > 0 ? (full < 4096 ? full : 4096) : 1;
    tau_loss_main<<<gblocks, THREADS, 0, stream>>>(
        (const float4*)tau, (const float4*)dt, tau, dt, out, n, inv_div);

    int bblocks = (nseg + THREADS - 1) / THREADS;
    if (bblocks > 0)
        tau_loss_boundary<<<bblocks, THREADS, 0, stream>>>(tau, dt, offsets, out, nseg, inv_div);
}

// Round 3
// 35.760 us; speedup vs baseline: 1.9858x; 1.9858x over previous
//
#include <hip/hip_runtime.h>

#define EPS 1e-5f
#define THREADS 256
#define MAIN_BLOCKS 2048
#define SUPER 2048               // float4 elements per block-iteration (32 KB/array)
#define BND_THREADS 256

// ---------------------------------------------------------------------------
// Kernel 1: full unmasked sum of nll = log(tau) + (dt+eps)/tau over all N.
// Each block-iteration covers one 2048-float4 superchunk per array. Each
// thread issues 16 independent dwordx4 loads (256 B/lane) before any compute.
// __launch_bounds__(256,4) caps at 128 VGPR so the loads actually stay in
// flight (R2 lesson: default heuristic chose 32 VGPR and serialized them).
// Partial sum -> ws[blockIdx.x] (plain store, no same-address atomics).
// ---------------------------------------------------------------------------
__global__ __launch_bounds__(THREADS, 4) void tau_loss_main(
    const float4* __restrict__ t4,
    const float4* __restrict__ d4,
    const float* __restrict__ tau,
    const float* __restrict__ dt,
    float* __restrict__ ws,
    int n) {
    const int n4 = n >> 2;
    const int nsuper = n4 / SUPER;

    float a0 = 0.f, a1 = 0.f, a2 = 0.f, a3 = 0.f;

    for (int s = blockIdx.x; s < nsuper; s += MAIN_BLOCKS) {
        const int base = s * SUPER + (int)threadIdx.x;
        // ---- issue all 16 loads back-to-back, no intervening use ----
        float4 t0 = t4[base + 0 * THREADS];
        float4 t1 = t4[base + 1 * THREADS];
        float4 t2 = t4[base + 2 * THREADS];
        float4 t3 = t4[base + 3 * THREADS];
        float4 t4v = t4[base + 4 * THREADS];
        float4 t5 = t4[base + 5 * THREADS];
        float4 t6 = t4[base + 6 * THREADS];
        float4 t7 = t4[base + 7 * THREADS];
        float4 e0 = d4[base + 0 * THREADS];
        float4 e1 = d4[base + 1 * THREADS];
        float4 e2 = d4[base + 2 * THREADS];
        float4 e3 = d4[base + 3 * THREADS];
        float4 e4 = d4[base + 4 * THREADS];
        float4 e5 = d4[base + 5 * THREADS];
        float4 e6 = d4[base + 6 * THREADS];
        float4 e7 = d4[base + 7 * THREADS];
        // ---- compute ----
        a0 += __logf(t0.x) + __fdividef(e0.x + EPS, t0.x);
        a1 += __logf(t0.y) + __fdividef(e0.y + EPS, t0.y);
        a2 += __logf(t0.z) + __fdividef(e0.z + EPS, t0.z);
        a3 += __logf(t0.w) + __fdividef(e0.w + EPS, t0.w);
        a0 += __logf(t1.x) + __fdividef(e1.x + EPS, t1.x);
        a1 += __logf(t1.y) + __fdividef(e1.y + EPS, t1.y);
        a2 += __logf(t1.z) + __fdividef(e1.z + EPS, t1.z);
        a3 += __logf(t1.w) + __fdividef(e1.w + EPS, t1.w);
        a0 += __logf(t2.x) + __fdividef(e2.x + EPS, t2.x);
        a1 += __logf(t2.y) + __fdividef(e2.y + EPS, t2.y);
        a2 += __logf(t2.z) + __fdividef(e2.z + EPS, t2.z);
        a3 += __logf(t2.w) + __fdividef(e2.w + EPS, t2.w);
        a0 += __logf(t3.x) + __fdividef(e3.x + EPS, t3.x);
        a1 += __logf(t3.y) + __fdividef(e3.y + EPS, t3.y);
        a2 += __logf(t3.z) + __fdividef(e3.z + EPS, t3.z);
        a3 += __logf(t3.w) + __fdividef(e3.w + EPS, t3.w);
        a0 += __logf(t4v.x) + __fdividef(e4.x + EPS, t4v.x);
        a1 += __logf(t4v.y) + __fdividef(e4.y + EPS, t4v.y);
        a2 += __logf(t4v.z) + __fdividef(e4.z + EPS, t4v.z);
        a3 += __logf(t4v.w) + __fdividef(e4.w + EPS, t4v.w);
        a0 += __logf(t5.x) + __fdividef(e5.x + EPS, t5.x);
        a1 += __logf(t5.y) + __fdividef(e5.y + EPS, t5.y);
        a2 += __logf(t5.z) + __fdividef(e5.z + EPS, t5.z);
        a3 += __logf(t5.w) + __fdividef(e5.w + EPS, t5.w);
        a0 += __logf(t6.x) + __fdividef(e6.x + EPS, t6.x);
        a1 += __logf(t6.y) + __fdividef(e6.y + EPS, t6.y);
        a2 += __logf(t6.z) + __fdividef(e6.z + EPS, t6.z);
        a3 += __logf(t6.w) + __fdividef(e6.w + EPS, t6.w);
        a0 += __logf(t7.x) + __fdividef(e7.x + EPS, t7.x);
        a1 += __logf(t7.y) + __fdividef(e7.y + EPS, t7.y);
        a2 += __logf(t7.z) + __fdividef(e7.z + EPS, t7.z);
        a3 += __logf(t7.w) + __fdividef(e7.w + EPS, t7.w);
    }

    // scalar tail: elements past nsuper*SUPER*4 (none for N=16.7M; kept general)
    if (blockIdx.x == 0) {
        for (int i = nsuper * (SUPER * 4) + (int)threadIdx.x; i < n; i += THREADS) {
            float t = tau[i];
            a0 += __logf(t) + __fdividef(dt[i] + EPS, t);
        }
    }

    float acc = (a0 + a1) + (a2 + a3);

    #pragma unroll
    for (int off = 32; off > 0; off >>= 1)
        acc += __shfl_down(acc, off, 64);

    __shared__ float smem[THREADS / 64];
    int wave = threadIdx.x >> 6;
    int lane = threadIdx.x & 63;
    if (lane == 0) smem[wave] = acc;
    __syncthreads();
    if (threadIdx.x == 0)
        ws[blockIdx.x] = smem[0] + smem[1] + smem[2] + smem[3];
}

// ---------------------------------------------------------------------------
// Kernel 2: boundary (first & last of each segment) contributions, negated,
// stored to ws[MAIN_BLOCKS + blockIdx.x].
// ---------------------------------------------------------------------------
__global__ __launch_bounds__(BND_THREADS) void tau_loss_boundary(
    const float* __restrict__ tau,
    const float* __restrict__ dt,
    const int* __restrict__ offsets,
    float* __restrict__ ws,
    int nseg) {
    int k = blockIdx.x * blockDim.x + threadIdx.x;

    float sub = 0.0f;
    if (k < nseg) {
        int s = offsets[k];
        int e = offsets[k + 1] - 1;
        float ts = tau[s];
        sub = __logf(ts) + __fdividef(dt[s] + EPS, ts);
        if (e != s) {
            float te = tau[e];
            sub += __logf(te) + __fdividef(dt[e] + EPS, te);
        }
    }

    #pragma unroll
    for (int off = 32; off > 0; off >>= 1)
        sub += __shfl_down(sub, off, 64);

    __shared__ float smem[BND_THREADS / 64];
    int wave = threadIdx.x >> 6;
    int lane = threadIdx.x & 63;
    if (lane == 0) smem[wave] = sub;
    __syncthreads();
    if (threadIdx.x == 0)
        ws[MAIN_BLOCKS + blockIdx.x] = -(smem[0] + smem[1] + smem[2] + smem[3]);
}

// ---------------------------------------------------------------------------
// Kernel 3: final reduce of the partial sums -> out[0].
// ---------------------------------------------------------------------------
__global__ __launch_bounds__(256) void tau_loss_final(
    const float* __restrict__ ws, int m, float inv_div,
    float* __restrict__ out) {
    float a = 0.f;
    for (int i = threadIdx.x; i < m; i += 256)
        a += ws[i];

    #pragma unroll
    for (int off = 32; off > 0; off >>= 1)
        a += __shfl_down(a, off, 64);

    __shared__ float smem[4];
    int wave = threadIdx.x >> 6;
    int lane = threadIdx.x & 63;
    if (lane == 0) smem[wave] = a;
    __syncthreads();
    if (threadIdx.x == 0)
        out[0] = (smem[0] + smem[1] + smem[2] + smem[3]) * inv_div;
}

extern "C" void kernel_launch(void* const* d_in, const int* in_sizes, int n_in,
                              void* d_out, int out_size, void* d_ws, size_t ws_size,
                              hipStream_t stream) {
    const float* tau = (const float*)d_in[0];
    const float* dt  = (const float*)d_in[1];
    const int* offsets = (const int*)d_in[2];
    float* out = (float*)d_out;
    float* ws = (float*)d_ws;

    const int n = in_sizes[0];
    const int n_off = in_sizes[2];          // B + 1
    const int nseg = n_off - 1;
    const float inv_div = 1.0f / (float)n_off;

    tau_loss_main<<<MAIN_BLOCKS, THREADS, 0, stream>>>(
        (const float4*)tau, (const float4*)dt, tau, dt, ws, n);

    int bblocks = (nseg + BND_THREADS - 1) / BND_THREADS;
    if (bblocks < 1) bblocks = 1;
    tau_loss_boundary<<<bblocks, BND_THREADS, 0, stream>>>(tau, dt, offsets, ws, nseg);

    tau_loss_final<<<1, 256, 0, stream>>>(ws, MAIN_BLOCKS + bblocks, inv_div, out);
}